// Round 6
// baseline (194.523 us; speedup 1.0000x reference)
//
#include <hip/hip_runtime.h>

// ContrastiveEmbeddingLoss, N=8192, D=128, C=100, margin=1.
// loss = [ sum_{y_i!=y_j} d_ij + N*margin + sum_{same,i!=j} max(margin-d_ij,0) ] / N^2
//   dissim = 2*sum_c SQ_c*(N - n_c) - 2*||S||^2 + 2*SSsum
//     SQ_c = sum_{i in c}||x_i||^2,  S = sum_i x_i,  SSsum = sum_c sum_{a,b in c} x_a.x_b
// Only same-class pairs (~N^2/100) need explicit d -> per-class fp16 MFMA Gram.
//
// 2 graph nodes: memset(7.7KB) -> fused kernel:
//   Phase A: rank (LDS histogram + per-class atomics) + coalesced x pass,
//            rows kept in registers across the rank atomics; class-grouped
//            fp16 rows to gh, sqnorms, replicated Scol/SQc atomics.
//   Grid barrier: threadfence-all + release add + acquire spin (512 blocks,
//            __launch_bounds__(256,2) -> 2 blocks/CU co-resident, no deadlock).
//   Phase B: MFMA Gram hinge, 2048 waves ~1 tile-pair each; done-counter,
//            last block runs the tiny double-precision finalize.

#define N_ROWS 8192
#define DIM    128
#define NCLS   100
#define CAP    224            // Binom(8192,0.01): mean 82, sd 9 -> +15 sigma
#define NBLK   512            // 16 rows per block
#define NREP   8              // atomic replication for Scol/SQc

typedef _Float16 half8  __attribute__((ext_vector_type(8)));
typedef _Float16 half4v __attribute__((ext_vector_type(4)));
typedef float    float4v __attribute__((ext_vector_type(4)));

__global__ __launch_bounds__(256, 2) void fused_kernel(
    const float* __restrict__ x, const int* __restrict__ y,
    _Float16* __restrict__ gh, float* __restrict__ sqg,
    float* __restrict__ Scol8, float* __restrict__ SQc8,
    float* __restrict__ Hsum, float* __restrict__ SSsum,
    int* __restrict__ cnt, int* __restrict__ doneA, int* __restrict__ doneB,
    float* __restrict__ out)
{
    const int b = blockIdx.x, tid = threadIdx.x;
    const int l = tid & 31, g = tid >> 5;        // 32 lanes/row-pass, 8 groups
    const int r0 = b * 16;
    const int rep = b & (NREP - 1);

    __shared__ int   ycls[16], intra[16];
    __shared__ int   lcnt[NCLS], lbase[NCLS];
    __shared__ float4 colred[256];
    __shared__ float wred[8];
    __shared__ int   lastFlag;

    // ---------------- Phase A: rank + single coalesced pass over x ----------
    const float4* x4 = (const float4*)x;
    float4 v0 = x4[(r0 + g) * 32 + l];           // rows r0+g and r0+8+g,
    float4 v1 = x4[(r0 + 8 + g) * 32 + l];       // both issued immediately

    if (tid < NCLS) lcnt[tid] = 0;
    if (tid < 16)   ycls[tid] = y[r0 + tid];
    __syncthreads();
    if (tid < 16)   intra[tid] = atomicAdd(&lcnt[ycls[tid]], 1);
    __syncthreads();
    if (tid < NCLS && lcnt[tid] > 0)
        lbase[tid] = atomicAdd(&cnt[tid], lcnt[tid]);   // <=16 atomics/block
    __syncthreads();

    float s0 = v0.x*v0.x + v0.y*v0.y + v0.z*v0.z + v0.w*v0.w;
    float s1 = v1.x*v1.x + v1.y*v1.y + v1.z*v1.z + v1.w*v1.w;
    #pragma unroll
    for (int off = 1; off < 32; off <<= 1) {
        s0 += __shfl_xor(s0, off);
        s1 += __shfl_xor(s1, off);
    }
    const int c0 = ycls[g],     p0 = lbase[c0] + intra[g];
    const int c1 = ycls[8 + g], p1 = lbase[c1] + intra[8 + g];
    if (p0 < CAP) {                              // never false in practice
        half4v h; h[0]=(_Float16)v0.x; h[1]=(_Float16)v0.y; h[2]=(_Float16)v0.z; h[3]=(_Float16)v0.w;
        *(half4v*)(gh + (size_t)(c0 * CAP + p0) * DIM + l * 4) = h;
        if (l == 0) sqg[c0 * CAP + p0] = s0;
    }
    if (p1 < CAP) {
        half4v h; h[0]=(_Float16)v1.x; h[1]=(_Float16)v1.y; h[2]=(_Float16)v1.z; h[3]=(_Float16)v1.w;
        *(half4v*)(gh + (size_t)(c1 * CAP + p1) * DIM + l * 4) = h;
        if (l == 0) sqg[c1 * CAP + p1] = s1;
    }
    if (l == 0) {
        atomicAdd(&SQc8[rep * NCLS + c0], s0);
        atomicAdd(&SQc8[rep * NCLS + c1], s1);
    }
    colred[tid] = make_float4(v0.x+v1.x, v0.y+v1.y, v0.z+v1.z, v0.w+v1.w);
    __syncthreads();
    if (tid < 32) {
        float4 a = colred[tid];
        #pragma unroll
        for (int gg = 1; gg < 8; ++gg) {
            float4 t = colred[tid + 32 * gg];
            a.x += t.x; a.y += t.y; a.z += t.z; a.w += t.w;
        }
        float* dst = Scol8 + rep * DIM;
        atomicAdd(&dst[4 * tid + 0], a.x);
        atomicAdd(&dst[4 * tid + 1], a.y);
        atomicAdd(&dst[4 * tid + 2], a.z);
        atomicAdd(&dst[4 * tid + 3], a.w);
    }

    // ---------------- Grid barrier (all 512 blocks co-resident) -------------
    __threadfence();                             // each thread releases its stores
    __syncthreads();
    if (tid == 0) {
        __hip_atomic_fetch_add(doneA, 1, __ATOMIC_RELEASE, __HIP_MEMORY_SCOPE_AGENT);
        while (__hip_atomic_load(doneA, __ATOMIC_ACQUIRE, __HIP_MEMORY_SCOPE_AGENT) < NBLK)
            __builtin_amdgcn_s_sleep(8);
    }
    __syncthreads();
    __threadfence();                             // acquire side: invalidate stale

    // ---------------- Phase B: per-class MFMA Gram hinge ---------------------
    const int wave = tid >> 6, lane = tid & 63;
    const int lr = lane & 15, q = lane >> 4;
    const int W = b * 4 + wave;                  // 0..2047
    const int c = W % 100, k = W / 100;          // 20 waves per class (k<20)
    float hacc = 0.f, dsum = 0.f;

    const int mtrue = __hip_atomic_load(&cnt[c], __ATOMIC_RELAXED, __HIP_MEMORY_SCOPE_AGENT);
    const int m = mtrue < CAP ? mtrue : CAP;
    const int ntiles = (m + 15) >> 4;
    const int ntp = ntiles * (ntiles + 1) / 2;   // ~21 typical
    const _Float16* base = gh + (size_t)c * CAP * DIM;
    const float* sqb_ = sqg + c * CAP;

    if (k < 20) {
        for (int tp = k; tp < ntp; tp += 20) {
            int ta = 0, rem = tp;
            while (rem >= ntiles - ta) { rem -= ntiles - ta; ++ta; }
            const int tb = ta + rem;
            // Pad rows hold benign fp16 poison (no NaN/Inf); outputs gated.
            const half8* ap = (const half8*)(base + (ta * 16 + lr) * DIM + q * 8);
            const half8* bp = (const half8*)(base + (tb * 16 + lr) * DIM + q * 8);
            float4v acc = {0.f, 0.f, 0.f, 0.f};
            #pragma unroll
            for (int kb = 0; kb < 4; ++kb)       // +32 halves per K block
                acc = __builtin_amdgcn_mfma_f32_16x16x32_f16(ap[kb * 4], bp[kb * 4], acc, 0, 0, 0);
            const float w = (ta == tb) ? 1.f : 2.f;
            const int bb = tb * 16 + lr;         // C/D col = lane & 15
            const float sqb = (bb < m) ? sqb_[bb] : 0.f;
            #pragma unroll
            for (int i = 0; i < 4; ++i) {
                const int a = ta * 16 + q * 4 + i;  // C/D row = quad*4 + reg
                if (a < m && bb < m) {
                    const float dot = acc[i];
                    dsum += w * dot;             // includes diagonal a==bb
                    if (a != bb) {
                        float d = fmaxf(sqb_[a] + sqb - 2.f * dot, 0.f);
                        hacc += w * fmaxf(1.f - d, 0.f);
                    }
                }
            }
        }
    }
    #pragma unroll
    for (int off = 32; off > 0; off >>= 1) {
        hacc += __shfl_xor(hacc, off);
        dsum += __shfl_xor(dsum, off);
    }
    if (lane == 0) { wred[wave] = hacc; wred[4 + wave] = dsum; }
    __syncthreads();
    if (tid == 0) {
        float h = wred[0] + wred[1] + wred[2] + wred[3];
        float d = wred[4] + wred[5] + wred[6] + wred[7];
        if (h != 0.f) atomicAdd(Hsum, h);
        if (d != 0.f) atomicAdd(SSsum, d);
        __threadfence();
        int p = __hip_atomic_fetch_add(doneB, 1, __ATOMIC_ACQ_REL, __HIP_MEMORY_SCOPE_AGENT);
        lastFlag = (p == NBLK - 1);
    }
    __syncthreads();
    if (!lastFlag) return;

    // ---------------- fused finalize (last-arriving block only) --------------
    __threadfence();
    const double Nf = (double)N_ROWS;
    double contrib = 0.0;
    if (tid < DIM) {                             // -2 ||S||^2
        float sc = 0.f;
        #pragma unroll
        for (int kk = 0; kk < NREP; ++kk) sc += Scol8[kk * DIM + tid];
        contrib -= 2.0 * (double)sc * (double)sc;
    }
    if (tid < NCLS) {                            // 2 SQ_c (N - n_c)
        float qv = 0.f;
        #pragma unroll
        for (int kk = 0; kk < NREP; ++kk) qv += SQc8[kk * NCLS + tid];
        int nc = __hip_atomic_load(&cnt[tid], __ATOMIC_RELAXED, __HIP_MEMORY_SCOPE_AGENT);
        contrib += 2.0 * (double)qv * (Nf - (double)nc);
    }
    if (tid == 0) {
        float H  = __hip_atomic_load(Hsum,  __ATOMIC_RELAXED, __HIP_MEMORY_SCOPE_AGENT);
        float SS = __hip_atomic_load(SSsum, __ATOMIC_RELAXED, __HIP_MEMORY_SCOPE_AGENT);
        contrib += 2.0 * (double)SS + (double)H + Nf * 1.0 /* N*margin */;
    }
    __shared__ double dred[256];
    dred[tid] = contrib;
    __syncthreads();
    for (int s = 128; s > 0; s >>= 1) {
        if (tid < s) dred[tid] += dred[tid + s];
        __syncthreads();
    }
    if (tid == 0) out[0] = (float)(dred[0] / (Nf * Nf));
}

extern "C" void kernel_launch(void* const* d_in, const int* in_sizes, int n_in,
                              void* d_out, int out_size, void* d_ws, size_t ws_size,
                              hipStream_t stream) {
    const float* x = (const float*)d_in[0];
    const int*   y = (const int*)d_in[1];

    _Float16* gh = (_Float16*)d_ws;                         // 100*224*128 fp16 = 5.73 MB
    float* sqg   = (float*)(gh + (size_t)NCLS * CAP * DIM); // 100*224
    // ---- zero region (single small memset): ----
    float* Scol8 = sqg + NCLS * CAP;         // NREP*128
    float* SQc8  = Scol8 + NREP * DIM;       // NREP*100
    float* Hsum  = SQc8 + NREP * NCLS;       // 1
    float* SSsum = Hsum + 1;                 // 1
    int*   cnt   = (int*)(SSsum + 1);        // 100
    int*   doneA = cnt + NCLS;               // 1
    int*   doneB = doneA + 1;                // 1
    const size_t zero_words = NREP * DIM + NREP * NCLS + 2 + NCLS + 2; // 1928

    hipMemsetAsync(Scol8, 0, zero_words * sizeof(float), stream);
    fused_kernel<<<NBLK, 256, 0, stream>>>(x, y, gh, sqg, Scol8, SQc8,
                                           Hsum, SSsum, cnt, doneA, doneB,
                                           (float*)d_out);
}

// Round 7
// 103.385 us; speedup vs baseline: 1.8815x; 1.8815x over previous
//
#include <hip/hip_runtime.h>

// ContrastiveEmbeddingLoss, N=8192, D=128, C=100, margin=1.
// loss = [ sum_{y_i!=y_j} d_ij + N*margin + sum_{same,i!=j} max(margin-d_ij,0) ] / N^2
//   dissim = 2*sum_c SQ_c*(N - n_c) - 2*||S||^2 + 2*SSsum
//     SQ_c = sum_{i in c}||x_i||^2,  S = sum_i x_i,  SSsum = sum_c sum_{a,b in c} x_a.x_b
// Only same-class pairs (~N^2/100) need explicit d -> per-class fp16 MFMA Gram.
//
// 3 graph nodes (R6's in-kernel grid barrier measured 3.4x WORSE than separate
// launches -- agent-scope spin ~140us; do not reintroduce):
//   rank (1 block): LDS histogram + prefix -> rank[], cnt[]; zeroes control ws.
//   scan (512 blocks): coalesced x pass, placement precomputed -> pure MLP.
//   gram (800 blocks): MFMA Gram hinge; last block (done-counter) finalizes.

#define N_ROWS 8192
#define DIM    128
#define NCLS   100
#define CAP    224            // Binom(8192,0.01): mean 82, sd 9 -> +15 sigma
#define SCB    512            // scan blocks (16 rows each)
#define GBPC   8              // gram blocks per class
#define GRAMB  (NCLS * GBPC)  // 800
#define NREP   8              // atomic replication for Scol/SQc
#define ZWORDS (NREP * DIM + NREP * NCLS + 3)   // Scol8+SQc8+Hsum+SSsum+doneB

typedef _Float16 half8  __attribute__((ext_vector_type(8)));
typedef _Float16 half4v __attribute__((ext_vector_type(4)));
typedef float    float4v __attribute__((ext_vector_type(4)));

// ---- Kernel 0 (1 block, 1024 thr): ranks via LDS histogram + prefix scan ----
__global__ __launch_bounds__(1024) void rank_kernel(
    const int* __restrict__ y, int* __restrict__ cnt, int* __restrict__ rank,
    float* __restrict__ zregion)
{
    const int tid = threadIdx.x;
    __shared__ int lcnt[NCLS], lbase[NCLS], pfx[128];

    for (int i = tid; i < ZWORDS; i += 1024) zregion[i] = 0.f;  // control ws
    if (tid < NCLS) lcnt[tid] = 0;
    __syncthreads();

    int yv[8], ord[8];
    #pragma unroll
    for (int k = 0; k < 8; ++k) yv[k] = y[tid + k * 1024];      // coalesced
    #pragma unroll
    for (int k = 0; k < 8; ++k) ord[k] = atomicAdd(&lcnt[yv[k]], 1);
    __syncthreads();

    if (tid < NCLS) cnt[tid] = lcnt[tid];
    if (tid < 128)  pfx[tid] = (tid < NCLS) ? lcnt[tid] : 0;
    __syncthreads();
    for (int off = 1; off < 128; off <<= 1) {                   // Hillis-Steele
        int v = 0;
        if (tid < 128) { v = pfx[tid]; if (tid >= off) v += pfx[tid - off]; }
        __syncthreads();
        if (tid < 128) pfx[tid] = v;
        __syncthreads();
    }
    if (tid < NCLS) lbase[tid] = pfx[tid] - lcnt[tid];          // exclusive
    __syncthreads();
    #pragma unroll
    for (int k = 0; k < 8; ++k)
        rank[tid + k * 1024] = lbase[yv[k]] + ord[k];
}

// ---- Kernel 1 (512 blocks): one coalesced pass over x, all stores free ------
__global__ __launch_bounds__(256) void scan_kernel(
    const float* __restrict__ x, const int* __restrict__ y,
    const int* __restrict__ rank,
    _Float16* __restrict__ gh, float* __restrict__ sqg,
    float* __restrict__ Scol8, float* __restrict__ SQc8)
{
    const int b = blockIdx.x, tid = threadIdx.x;
    const int l = tid & 31, g = tid >> 5;        // 32 lanes/row, 8 groups
    const int r0 = b * 16;
    const int rep = b & (NREP - 1);
    const float4* x4 = (const float4*)x;
    __shared__ int    ycls[16], rnk[16];
    __shared__ float4 colred[256];

    float4 v0 = x4[(r0 + g) * 32 + l];           // both rows issued up front
    float4 v1 = x4[(r0 + 8 + g) * 32 + l];
    if (tid < 16) { ycls[tid] = y[r0 + tid]; rnk[tid] = rank[r0 + tid]; }

    float s0 = v0.x*v0.x + v0.y*v0.y + v0.z*v0.z + v0.w*v0.w;
    float s1 = v1.x*v1.x + v1.y*v1.y + v1.z*v1.z + v1.w*v1.w;
    #pragma unroll
    for (int off = 1; off < 32; off <<= 1) {
        s0 += __shfl_xor(s0, off);
        s1 += __shfl_xor(s1, off);
    }
    __syncthreads();
    const int c0 = ycls[g],     p0 = rnk[g];
    const int c1 = ycls[8 + g], p1 = rnk[8 + g];
    if (p0 < CAP) {                              // never false in practice
        half4v h; h[0]=(_Float16)v0.x; h[1]=(_Float16)v0.y; h[2]=(_Float16)v0.z; h[3]=(_Float16)v0.w;
        *(half4v*)(gh + (size_t)(c0 * CAP + p0) * DIM + l * 4) = h;
        if (l == 0) sqg[c0 * CAP + p0] = s0;
    }
    if (p1 < CAP) {
        half4v h; h[0]=(_Float16)v1.x; h[1]=(_Float16)v1.y; h[2]=(_Float16)v1.z; h[3]=(_Float16)v1.w;
        *(half4v*)(gh + (size_t)(c1 * CAP + p1) * DIM + l * 4) = h;
        if (l == 0) sqg[c1 * CAP + p1] = s1;
    }
    if (l == 0) {
        atomicAdd(&SQc8[rep * NCLS + c0], s0);
        atomicAdd(&SQc8[rep * NCLS + c1], s1);
    }
    colred[tid] = make_float4(v0.x+v1.x, v0.y+v1.y, v0.z+v1.z, v0.w+v1.w);
    __syncthreads();
    if (tid < 32) {
        float4 a = colred[tid];
        #pragma unroll
        for (int gg = 1; gg < 8; ++gg) {
            float4 t = colred[tid + 32 * gg];
            a.x += t.x; a.y += t.y; a.z += t.z; a.w += t.w;
        }
        float* dst = Scol8 + rep * DIM;
        atomicAdd(&dst[4 * tid + 0], a.x);
        atomicAdd(&dst[4 * tid + 1], a.y);
        atomicAdd(&dst[4 * tid + 2], a.z);
        atomicAdd(&dst[4 * tid + 3], a.w);
    }
}

// ---- Kernel 2 (800 blocks): per-class MFMA Gram hinge + fused finalize ------
__global__ __launch_bounds__(256) void gram_kernel(
    const _Float16* __restrict__ gh, const float* __restrict__ sqg,
    const int* __restrict__ cnt,
    const float* __restrict__ Scol8, const float* __restrict__ SQc8,
    float* __restrict__ Hsum, float* __restrict__ SSsum,
    int* __restrict__ done, float* __restrict__ out)
{
    const int c = blockIdx.x >> 3, qq = blockIdx.x & 7, tid = threadIdx.x;
    __shared__ float wred[8];
    __shared__ int   lastFlag;

    const int mtrue = cnt[c];
    const int m = mtrue < CAP ? mtrue : CAP;
    const int ntiles = (m + 15) >> 4;
    const int ntp = ntiles * (ntiles + 1) / 2;   // ~21 for m~82

    const int wave = tid >> 6, lane = tid & 63;
    const int lr = lane & 15, q = lane >> 4;
    float hacc = 0.f, dsum = 0.f;
    const _Float16* base = gh + (size_t)c * CAP * DIM;
    const float* sqb_ = sqg + c * CAP;

    for (int tp = qq * 4 + wave; tp < ntp; tp += 32) {   // <=1 pair/wave typ.
        int ta = 0, rem = tp;
        while (rem >= ntiles - ta) { rem -= ntiles - ta; ++ta; }
        const int tb = ta + rem;
        // Pad rows hold benign fp16 poison (no NaN/Inf); outputs gated below.
        const half8* ap = (const half8*)(base + (ta * 16 + lr) * DIM + q * 8);
        const half8* bp = (const half8*)(base + (tb * 16 + lr) * DIM + q * 8);
        float4v acc = {0.f, 0.f, 0.f, 0.f};
        #pragma unroll
        for (int kb = 0; kb < 4; ++kb)               // +32 halves per K block
            acc = __builtin_amdgcn_mfma_f32_16x16x32_f16(ap[kb * 4], bp[kb * 4], acc, 0, 0, 0);
        const float w = (ta == tb) ? 1.f : 2.f;
        const int bb = tb * 16 + lr;                 // C/D col = lane & 15
        const float sqb = (bb < m) ? sqb_[bb] : 0.f;
        #pragma unroll
        for (int i = 0; i < 4; ++i) {
            const int a = ta * 16 + q * 4 + i;       // C/D row = quad*4 + reg
            if (a < m && bb < m) {
                const float dot = acc[i];
                dsum += w * dot;                     // includes diagonal a==bb
                if (a != bb) {
                    float d = fmaxf(sqb_[a] + sqb - 2.f * dot, 0.f);
                    hacc += w * fmaxf(1.f - d, 0.f);
                }
            }
        }
    }
    #pragma unroll
    for (int off = 32; off > 0; off >>= 1) {
        hacc += __shfl_xor(hacc, off);
        dsum += __shfl_xor(dsum, off);
    }
    if (lane == 0) { wred[wave] = hacc; wred[4 + wave] = dsum; }
    __syncthreads();
    if (tid == 0) {
        float h = wred[0] + wred[1] + wred[2] + wred[3];
        float d = wred[4] + wred[5] + wred[6] + wred[7];
        if (h != 0.f) atomicAdd(Hsum, h);
        if (d != 0.f) atomicAdd(SSsum, d);
        __threadfence();                             // release before counting
        int p = atomicAdd(done, 1);
        lastFlag = (p == GRAMB - 1);
    }
    __syncthreads();
    if (!lastFlag) return;

    // ---------------- fused finalize (last-arriving block only) ------------
    __threadfence();                                 // acquire others' results
    const double Nf = (double)N_ROWS;
    double contrib = 0.0;
    if (tid < DIM) {                                 // -2 ||S||^2
        float sc = 0.f;
        #pragma unroll
        for (int k = 0; k < NREP; ++k) sc += Scol8[k * DIM + tid];
        contrib -= 2.0 * (double)sc * (double)sc;
    }
    if (tid < NCLS) {                                // 2 SQ_c (N - n_c)
        float qv = 0.f;
        #pragma unroll
        for (int k = 0; k < NREP; ++k) qv += SQc8[k * NCLS + tid];
        contrib += 2.0 * (double)qv * (Nf - (double)cnt[tid]);
    }
    if (tid == 0) {
        float H  = __hip_atomic_load(Hsum,  __ATOMIC_RELAXED, __HIP_MEMORY_SCOPE_AGENT);
        float SS = __hip_atomic_load(SSsum, __ATOMIC_RELAXED, __HIP_MEMORY_SCOPE_AGENT);
        contrib += 2.0 * (double)SS + (double)H + Nf * 1.0 /* N*margin */;
    }
    __shared__ double dred[256];
    dred[tid] = contrib;
    __syncthreads();
    for (int s = 128; s > 0; s >>= 1) {
        if (tid < s) dred[tid] += dred[tid + s];
        __syncthreads();
    }
    if (tid == 0) out[0] = (float)(dred[0] / (Nf * Nf));
}

extern "C" void kernel_launch(void* const* d_in, const int* in_sizes, int n_in,
                              void* d_out, int out_size, void* d_ws, size_t ws_size,
                              hipStream_t stream) {
    const float* x = (const float*)d_in[0];
    const int*   y = (const int*)d_in[1];

    _Float16* gh = (_Float16*)d_ws;                         // 100*224*128 fp16 = 5.73 MB
    float* sqg   = (float*)(gh + (size_t)NCLS * CAP * DIM); // 100*224
    int*   rank  = (int*)(sqg + NCLS * CAP);                // 8192
    // ---- control region (zeroed by rank_kernel): ----
    float* Scol8 = (float*)(rank + N_ROWS);  // NREP*128
    float* SQc8  = Scol8 + NREP * DIM;       // NREP*100
    float* Hsum  = SQc8 + NREP * NCLS;       // 1
    float* SSsum = Hsum + 1;                 // 1
    int*   done  = (int*)(SSsum + 1);        // 1   (end of ZWORDS region)
    int*   cnt   = done + 1;                 // 100 (written by rank_kernel)

    rank_kernel<<<1,     1024, 0, stream>>>(y, cnt, rank, Scol8);
    scan_kernel<<<SCB,   256,  0, stream>>>(x, y, rank, gh, sqg, Scol8, SQc8);
    gram_kernel<<<GRAMB, 256,  0, stream>>>(gh, sqg, cnt, Scol8, SQc8,
                                            Hsum, SSsum, done, (float*)d_out);
}